// Round 5
// baseline (59.868 us; speedup 1.0000x reference)
//
#include <hip/hip_runtime.h>
#include <math.h>

#define NSLOT 5
#define EPSF 1e-8f

typedef float f4 __attribute__((ext_vector_type(4)));

// Inline-asm global load: compiler cannot re-roll or serialize these; they
// issue in program order and vmcnt counts them in order (loads retire FIFO).
#define GLOAD(dst, ptr) \
    asm volatile("global_load_dwordx4 %0, %1, off" : "=v"(dst) : "v"(ptr) : "memory")

// Counted wait + scheduling fence (rule #18: without sched_barrier the
// scheduler hoists register-only FMAs above the waitcnt).
#define WAITCNT(n) do { \
    asm volatile("s_waitcnt vmcnt(" #n ")" ::: "memory"); \
    __builtin_amdgcn_sched_barrier(0); \
} while (0)

#define ISSUE_K(b, j) do { \
    GLOAD(qb[b],    qp  + (j) * 64); \
    GLOAD(kb[b][0], kp0 + (j) * 64); \
    GLOAD(kb[b][1], kp1 + (j) * 64); \
    GLOAD(kb[b][2], kp2 + (j) * 64); \
    GLOAD(kb[b][3], kp3 + (j) * 64); \
    GLOAD(kb[b][4], kp4 + (j) * 64); \
} while (0)

#define DOT1(s, t) do { \
    dot[s] = fmaf(q.x, t.x, fmaf(q.y, t.y, fmaf(q.z, t.z, fmaf(q.w, t.w, dot[s])))); \
    kk[s]  = fmaf(t.x, t.x, fmaf(t.y, t.y, fmaf(t.z, t.z, fmaf(t.w, t.w, kk[s])))); \
} while (0)

#define CONSUME_K(b) do { \
    f4 q = qb[b]; \
    qq = fmaf(q.x, q.x, fmaf(q.y, q.y, fmaf(q.z, q.z, fmaf(q.w, q.w, qq)))); \
    { f4 t = kb[b][0]; DOT1(0, t); } \
    { f4 t = kb[b][1]; DOT1(1, t); } \
    { f4 t = kb[b][2]; DOT1(2, t); } \
    { f4 t = kb[b][3]; DOT1(3, t); } \
    { f4 t = kb[b][4]; DOT1(4, t); } \
} while (0)

#define ISSUE_V(b, m) do { \
    GLOAD(vb[b][0], vp0 + (m) * 64); \
    GLOAD(vb[b][1], vp1 + (m) * 64); \
    GLOAD(vb[b][2], vp2 + (m) * 64); \
    GLOAD(vb[b][3], vp3 + (m) * 64); \
    GLOAD(vb[b][4], vp4 + (m) * 64); \
} while (0)

#define CONSUME_V(b, m) do { \
    f4 acc = vb[b][0] * w0; \
    acc += vb[b][1] * w1; \
    acc += vb[b][2] * w2; \
    acc += vb[b][3] * w3; \
    acc += vb[b][4] * w4; \
    op[(m) * 64] = acc; \
} while (0)

// One wave per sample; D=2048 -> 512 f4 chunks -> 8 chunks of 64 lanes.
__global__ __launch_bounds__(64, 3) void mb_pipe_kernel(
    const float* __restrict__ query,
    const int*   __restrict__ labels,
    const float* __restrict__ mkeys,
    const float* __restrict__ mvals,
    const float* __restrict__ qscores,
    const int*   __restrict__ topk_p,
    float* __restrict__ out_ret,
    float* __restrict__ out_w,
    int B)
{
    const int lane = threadIdx.x;
    const int i    = blockIdx.x;
    if (i >= B) return;

    const int c = labels[i];
    int k = topk_p[0];
    if (k > NSLOT) k = NSLOT;
    if (k < 1) k = 1;

    // scores loaded & materialized BEFORE the asm section so the compiler's
    // own waitcnt for them lands here, not inside the pipeline.
    float sc0 = qscores[(size_t)c * NSLOT + 0];
    float sc1 = qscores[(size_t)c * NSLOT + 1];
    float sc2 = qscores[(size_t)c * NSLOT + 2];
    float sc3 = qscores[(size_t)c * NSLOT + 3];
    float sc4 = qscores[(size_t)c * NSLOT + 4];
    asm volatile("" : "+v"(sc0), "+v"(sc1), "+v"(sc2), "+v"(sc3), "+v"(sc4));

    const int n4 = 512;                       // D = 2048
    const f4* q4 = reinterpret_cast<const f4*>(query) + (size_t)i * n4;
    const f4* k4 = reinterpret_cast<const f4*>(mkeys) + (size_t)c * NSLOT * n4;
    const f4* v4 = reinterpret_cast<const f4*>(mvals) + (size_t)c * NSLOT * n4;
    f4*       o4 = reinterpret_cast<f4*>(out_ret) + (size_t)i * n4;

    const f4* qp  = q4 + lane;
    const f4* kp0 = k4 + lane;
    const f4* kp1 = k4 + 512 + lane;
    const f4* kp2 = k4 + 1024 + lane;
    const f4* kp3 = k4 + 1536 + lane;
    const f4* kp4 = k4 + 2048 + lane;
    const f4* vp0 = v4 + lane;
    const f4* vp1 = v4 + 512 + lane;
    const f4* vp2 = v4 + 1024 + lane;
    const f4* vp3 = v4 + 1536 + lane;
    const f4* vp4 = v4 + 2048 + lane;
    f4*       op  = o4 + lane;

    float qq = 0.f;
    float dot[NSLOT] = {0.f, 0.f, 0.f, 0.f, 0.f};
    float kk[NSLOT]  = {0.f, 0.f, 0.f, 0.f, 0.f};

    f4 qb[3];
    f4 kb[3][NSLOT];
    f4 vb[3][NSLOT];

    // ---- pass 1 pipeline: depth 3 groups of 6 loads; vmcnt never drains ----
    ISSUE_K(0, 0); ISSUE_K(1, 1); ISSUE_K(2, 2);
    WAITCNT(12); CONSUME_K(0); ISSUE_K(0, 3);
    WAITCNT(12); CONSUME_K(1); ISSUE_K(1, 4);
    WAITCNT(12); CONSUME_K(2); ISSUE_K(2, 5);
    WAITCNT(12); CONSUME_K(0); ISSUE_K(0, 6);
    WAITCNT(12); CONSUME_K(1); ISSUE_K(1, 7);
    WAITCNT(12); CONSUME_K(2); ISSUE_V(0, 0);
    WAITCNT(11); CONSUME_K(0); ISSUE_V(1, 1);
    WAITCNT(10); CONSUME_K(1); ISSUE_V(2, 2);
    // K group 7 done; V chunks 0..2 (15 loads) stay in flight under the epilogue.

    // ---- butterfly reduce (VALU/DS only; V loads in flight underneath) ----
#pragma unroll
    for (int off = 1; off < 64; off <<= 1) {
        qq += __shfl_xor(qq, off);
#pragma unroll
        for (int s = 0; s < NSLOT; ++s) {
            dot[s] += __shfl_xor(dot[s], off);
            kk[s]  += __shfl_xor(kk[s], off);
        }
    }

    // ---- scalar epilogue (all lanes redundantly) ----
    float qn = fmaxf(sqrtf(qq), EPSF);
    float scr[NSLOT] = {sc0, sc1, sc2, sc3, sc4};
    float ssum = sc0 + sc1 + sc2 + sc3 + sc4;

    float comb[NSLOT];
#pragma unroll
    for (int s = 0; s < NSLOT; ++s) {
        float kn = fmaxf(sqrtf(kk[s]), EPSF);
        comb[s] = (dot[s] / (qn * kn)) * scr[s];
    }

    bool used[NSLOT];
#pragma unroll
    for (int s = 0; s < NSLOT; ++s) used[s] = false;
    float tsc[NSLOT];
    int   tix[NSLOT];
#pragma unroll
    for (int j = 0; j < NSLOT; ++j) {
        float best = -INFINITY;
        int bi = 0;
        if (j < k) {
#pragma unroll
            for (int s = 0; s < NSLOT; ++s) {
                if (!used[s] && comb[s] > best) { best = comb[s]; bi = s; }
            }
#pragma unroll
            for (int s = 0; s < NSLOT; ++s) used[s] = used[s] || (s == bi);
        }
        tsc[j] = best;
        tix[j] = bi;
    }

    const bool hit = (ssum != 0.0f);
    float m = tsc[0];
    float esum = 0.f, wsum = 0.f;
    float a[NSLOT];
#pragma unroll
    for (int j = 0; j < NSLOT; ++j) {
        if (j < k) {
            a[j] = __expf((tsc[j] - m) * 10.0f);   // 1/TEMP = 10
            esum += a[j];
            wsum += tsc[j];
        } else {
            a[j] = 0.f;
        }
    }
    float inv = hit ? (1.0f / esum) : 0.0f;

    float wgt[NSLOT];
#pragma unroll
    for (int s = 0; s < NSLOT; ++s) {
        float ws = 0.f;
#pragma unroll
        for (int j = 0; j < NSLOT; ++j)
            if (j < k && tix[j] == s) ws += a[j] * inv;
        wgt[s] = ws;
    }
    const float w0 = wgt[0], w1 = wgt[1], w2 = wgt[2], w3 = wgt[3], w4 = wgt[4];

    if (lane == 0) out_w[i] = hit ? (wsum / (float)k) : 0.0f;

    // ---- pass 2 pipeline: weighted sum of 5 value rows, depth 3 ----
    WAITCNT(10); CONSUME_V(0, 0); ISSUE_V(0, 3);
    WAITCNT(10); CONSUME_V(1, 1); ISSUE_V(1, 4);
    WAITCNT(10); CONSUME_V(2, 2); ISSUE_V(2, 5);
    WAITCNT(10); CONSUME_V(0, 3); ISSUE_V(0, 6);
    WAITCNT(10); CONSUME_V(1, 4); ISSUE_V(1, 7);
    WAITCNT(10); CONSUME_V(2, 5);
    WAITCNT(5);  CONSUME_V(0, 6);
    WAITCNT(0);  CONSUME_V(1, 7);
}

// Generic fallback for unexpected shapes (correctness only).
__global__ __launch_bounds__(64) void mb_generic_kernel(
    const float* __restrict__ query,
    const int*   __restrict__ labels,
    const float* __restrict__ mkeys,
    const float* __restrict__ mvals,
    const float* __restrict__ qscores,
    const int*   __restrict__ topk_p,
    float* __restrict__ out_ret,
    float* __restrict__ out_w,
    int B, int n4)
{
    const int lane = threadIdx.x;
    const int i    = blockIdx.x;
    if (i >= B) return;
    const int c = labels[i];
    int k = topk_p[0];
    if (k > NSLOT) k = NSLOT;
    if (k < 1) k = 1;

    const f4* q4 = reinterpret_cast<const f4*>(query) + (size_t)i * n4;
    const f4* k4 = reinterpret_cast<const f4*>(mkeys) + (size_t)c * NSLOT * n4;
    const f4* v4 = reinterpret_cast<const f4*>(mvals) + (size_t)c * NSLOT * n4;
    f4*       o4 = reinterpret_cast<f4*>(out_ret) + (size_t)i * n4;

    float qq = 0.f, dot[NSLOT] = {0}, kk[NSLOT] = {0};
    for (int idx = lane; idx < n4; idx += 64) {
        f4 q = q4[idx];
        qq = fmaf(q.x, q.x, fmaf(q.y, q.y, fmaf(q.z, q.z, fmaf(q.w, q.w, qq))));
        for (int s = 0; s < NSLOT; ++s) {
            f4 t = k4[s * n4 + idx];
            dot[s] = fmaf(q.x, t.x, fmaf(q.y, t.y, fmaf(q.z, t.z, fmaf(q.w, t.w, dot[s]))));
            kk[s]  = fmaf(t.x, t.x, fmaf(t.y, t.y, fmaf(t.z, t.z, fmaf(t.w, t.w, kk[s]))));
        }
    }
    for (int off = 1; off < 64; off <<= 1) {
        qq += __shfl_xor(qq, off);
        for (int s = 0; s < NSLOT; ++s) {
            dot[s] += __shfl_xor(dot[s], off);
            kk[s]  += __shfl_xor(kk[s], off);
        }
    }
    float qn = fmaxf(sqrtf(qq), EPSF);
    float scr[NSLOT], ssum = 0.f;
    for (int s = 0; s < NSLOT; ++s) { scr[s] = qscores[(size_t)c * NSLOT + s]; ssum += scr[s]; }
    float comb[NSLOT];
    for (int s = 0; s < NSLOT; ++s)
        comb[s] = (dot[s] / (qn * fmaxf(sqrtf(kk[s]), EPSF))) * scr[s];
    bool used[NSLOT] = {false, false, false, false, false};
    float tsc[NSLOT]; int tix[NSLOT];
    for (int j = 0; j < NSLOT; ++j) {
        float best = -INFINITY; int bi = 0;
        if (j < k) {
            for (int s = 0; s < NSLOT; ++s)
                if (!used[s] && comb[s] > best) { best = comb[s]; bi = s; }
            used[bi] = true;
        }
        tsc[j] = best; tix[j] = bi;
    }
    const bool hit = (ssum != 0.0f);
    float m = tsc[0], esum = 0.f, wsum = 0.f, a[NSLOT];
    for (int j = 0; j < NSLOT; ++j) {
        if (j < k) { a[j] = __expf((tsc[j] - m) * 10.0f); esum += a[j]; wsum += tsc[j]; }
        else a[j] = 0.f;
    }
    float inv = hit ? (1.0f / esum) : 0.0f;
    float w[NSLOT];
    for (int s = 0; s < NSLOT; ++s) {
        float ws = 0.f;
        for (int j = 0; j < NSLOT; ++j) if (j < k && tix[j] == s) ws += a[j] * inv;
        w[s] = ws;
    }
    if (lane == 0) out_w[i] = hit ? (wsum / (float)k) : 0.0f;
    for (int idx = lane; idx < n4; idx += 64) {
        f4 acc = (f4)(0.f);
        for (int s = 0; s < NSLOT; ++s) {
            f4 v = v4[s * n4 + idx];
            acc += v * w[s];
        }
        o4[idx] = acc;
    }
}

extern "C" void kernel_launch(void* const* d_in, const int* in_sizes, int n_in,
                              void* d_out, int out_size, void* d_ws, size_t ws_size,
                              hipStream_t stream) {
    const float* query   = (const float*)d_in[0];
    const int*   labels  = (const int*)d_in[1];
    const float* mkeys   = (const float*)d_in[2];
    const float* mvals   = (const float*)d_in[3];
    const float* qscores = (const float*)d_in[4];
    const int*   topk    = (const int*)d_in[5];

    const int B  = in_sizes[1];
    const int D  = in_sizes[0] / B;
    const int n4 = D >> 2;

    float* out_ret = (float*)d_out;
    float* out_w   = out_ret + (size_t)B * D;

    if (D == 2048) {
        mb_pipe_kernel<<<dim3(B), dim3(64), 0, stream>>>(
            query, labels, mkeys, mvals, qscores, topk, out_ret, out_w, B);
    } else {
        mb_generic_kernel<<<dim3(B), dim3(64), 0, stream>>>(
            query, labels, mkeys, mvals, qscores, topk, out_ret, out_w, B, n4);
    }
}